// Round 14
// baseline (87.029 us; speedup 1.0000x reference)
//
#include <hip/hip_runtime.h>
#include <cmath>

#define T_LEN 48000
#define L_CHUNK 128
#define N_CHUNKS 375
#define N_ROWS 124
#define SLOTS 1024          // 8 channels * 128 padded rows
#define ROWS_PER_BLK 64
#define XS_STRIDE 132       // p1 x tile stride (proven)
#define GRP 15
#define NGRP 25
#define SUB 32              // samples per lane in p3
#define WPW 2048            // samples per wave-window (64*32)
#define N_WIN 24            // ceil(48000/2048)

struct CoefF {
    float lp_b0, lp_b1, lp_b2, lp_a1, lp_a2;
    float bp_b0[7], bp_cr[7], bp_ci[7];
};
struct CoefD {
    double p00, p01, p10, p11;   // LP propagator (2x2)
    double Pr[7], Pi[7];         // resonator propagators (complex)
};

__device__ __forceinline__ void sel_M(int ch, const CoefD& D,
                                      double& m00, double& m01, double& m10, double& m11) {
    if (ch == 0) {
        m00 = D.p00; m01 = D.p01; m10 = D.p10; m11 = D.p11;
    } else {
        double Pr = 0.0, Pi = 0.0;
#pragma unroll
        for (int c = 1; c < 8; ++c) if (ch == c) { Pr = D.Pr[c - 1]; Pi = D.Pi[c - 1]; }
        m00 = Pr; m01 = -Pi; m10 = Pi; m11 = Pr;
    }
}

// ---- Phase 1: zero-init chunk scan; emit running states at 32/64/96 (wsS) and 128 (ws_fin) ----
__global__ __launch_bounds__(512) void mfb_p1(const float* __restrict__ x, CoefF C,
                                              float2* __restrict__ ws_fin,
                                              float2* __restrict__ wsS) {
    extern __shared__ __align__(16) float smem[];
    float* xs = smem;                                  // [64][XS_STRIDE]
    const int t     = threadIdx.x;
    const int j     = blockIdx.y;
    const int n0    = (int)blockIdx.x * ROWS_PER_BLK;
    const int tbase = j * L_CHUNK;

#pragma unroll
    for (int i = 0; i < 4; ++i) {
        int g = i * 512 + t;
        int r = g >> 5, c = (g & 31) * 4;
        int n = n0 + r;
        float4 v = make_float4(0.f, 0.f, 0.f, 0.f);
        if (n < N_ROWS)
            v = *reinterpret_cast<const float4*>(x + (size_t)n * T_LEN + tbase + c);
        *reinterpret_cast<float4*>(xs + r * XS_STRIDE + c) = v;
    }
    __syncthreads();

    const int ch = t >> 6, nn = t & 63;
    const int n  = n0 + nn;
    const int slot = ch * 128 + n;

    float f_b0, f_b1 = 0.f, f_b2 = 0.f, f_a1 = 0.f, f_a2 = 0.f, f_cr = 0.f, f_ci = 0.f;
    if (ch == 0) {
        f_b0 = C.lp_b0; f_b1 = C.lp_b1; f_b2 = C.lp_b2; f_a1 = C.lp_a1; f_a2 = C.lp_a2;
    } else {
        f_b0 = 0.f;
#pragma unroll
        for (int c = 1; c < 8; ++c)
            if (ch == c) { f_b0 = C.bp_b0[c - 1]; f_cr = C.bp_cr[c - 1]; f_ci = C.bp_ci[c - 1]; }
    }

    float s0 = 0.f, s1 = 0.f;
    for (int b = 0; b < 8; ++b) {
        float4 xv4[4];
#pragma unroll
        for (int q = 0; q < 4; ++q)
            xv4[q] = *reinterpret_cast<const float4*>(xs + nn * XS_STRIDE + b * 16 + q * 4);
        const float* xv = reinterpret_cast<const float*>(xv4);
        if (ch == 0) {
#pragma unroll
            for (int k = 0; k < 16; ++k) {
                float xvk = xv[k];
                float y  = fmaf(f_b0, xvk, s0);
                s0 = fmaf(f_b1, xvk, fmaf(-f_a1, y, s1));
                s1 = fmaf(f_b2, xvk, -f_a2 * y);
            }
        } else {
#pragma unroll
            for (int k = 0; k < 16; ++k) {
                float xvk = xv[k];
                float nyr = fmaf(f_cr, s0, fmaf(-f_ci, s1, f_b0 * xvk));
                float nyi = fmaf(f_cr, s1, f_ci * s0);
                s0 = nyr; s1 = nyi;
            }
        }
        if (b == 1 || b == 3 || b == 5)   // states after 32, 64, 96 samples
            wsS[(size_t)(j * 3 + (b >> 1)) * SLOTS + slot] = make_float2(s0, s1);
    }
    ws_fin[(size_t)j * SLOTS + slot] = make_float2(s0, s1);
}

// ---- Tree combine, stage A (unchanged) ----
__global__ __launch_bounds__(256) void mfb_groupsum(const float2* __restrict__ ws_fin,
                                                    float2* __restrict__ A, CoefD D) {
    int tid = blockIdx.x * 256 + (int)threadIdx.x;   // 0..25599
    int s = tid & 1023, g = tid >> 10;
    double m00, m01, m10, m11;
    sel_M(s >> 7, D, m00, m01, m10, m11);
    const float2* base = ws_fin + (size_t)g * GRP * SLOTS + s;
    float2 f[GRP];
#pragma unroll
    for (int i = 0; i < GRP; ++i) f[i] = base[(size_t)i * SLOTS];
    double a0 = 0.0, a1 = 0.0;
#pragma unroll
    for (int i = 0; i < GRP; ++i) {
        double t0 = m00 * a0 + m01 * a1 + (double)f[i].x;
        double t1 = m10 * a0 + m11 * a1 + (double)f[i].y;
        a0 = t0; a1 = t1;
    }
    A[(size_t)g * SLOTS + s] = make_float2((float)a0, (float)a1);
}

// ---- stage B (unchanged) ----
__global__ __launch_bounds__(256) void mfb_groupscan(const float2* __restrict__ A,
                                                     float2* __restrict__ U, CoefD D15) {
    int s = blockIdx.x * 256 + (int)threadIdx.x;     // 0..1023
    double m00, m01, m10, m11;
    sel_M(s >> 7, D15, m00, m01, m10, m11);
    float2 f[NGRP];
#pragma unroll
    for (int g = 0; g < NGRP; ++g) f[g] = A[(size_t)g * SLOTS + s];
    double u0 = 0.0, u1 = 0.0;
#pragma unroll
    for (int g = 0; g < NGRP; ++g) {
        U[(size_t)g * SLOTS + s] = make_float2((float)u0, (float)u1);
        double t0 = (double)f[g].x + m00 * u0 + m01 * u1;
        double t1 = (double)f[g].y + m10 * u0 + m11 * u1;
        u0 = t0; u1 = t1;
    }
}

// ---- Phase 3: lane = 32-sample sub-chunk; wave = 2048 consecutive samples of one
//      stream; block = 8 channel-waves sharing one staged x window.
//      Drain: 8 x 1KB fully-contiguous wave-stores (8KB sequential per row-visit).
__global__ __launch_bounds__(512) void mfb_out(const float* __restrict__ x,
                                               CoefF C, CoefD D, CoefD E1, CoefD D32_unused_pad,
                                               const float2* __restrict__ ws_fin,
                                               const float2* __restrict__ wsS,
                                               const float2* __restrict__ U,
                                               float* __restrict__ out) {
    extern __shared__ __align__(16) float smem[];     // 9 * 64*32 floats = 73728 B
    float* xsub = smem;                               // [64][32], XOR-swizzled
    const int t  = threadIdx.x;
    const int wv = t >> 6, L = t & 63;
    const int bid = (int)blockIdx.x;                  // 124 * 24
    const int n = bid / N_WIN, w = bid - n * N_WIN;
    const int ch = wv;
    const int slot = ch * 128 + n;
    float* tile = smem + 64 * 32 + wv * (64 * 32);    // per-wave [64][32], swizzled

    // ---- stage x window: 2048 floats, one float4/thread, fully coalesced ----
    {
        int p = t * 4;
        int off = w * WPW + p;
        float4 v = make_float4(0.f, 0.f, 0.f, 0.f);
        if (off < T_LEN)
            v = *reinterpret_cast<const float4*>(x + (size_t)n * T_LEN + off);
        int row = p >> 5;
        int col = (p & 31) ^ ((row & 7) << 2);        // XOR swizzle (float units)
        *reinterpret_cast<float4*>(xsub + row * 32 + col) = v;
    }
    __syncthreads();

    const bool act = (w * WPW + L * SUB) < T_LEN;

    float f_b0, f_b1 = 0.f, f_b2 = 0.f, f_a1 = 0.f, f_a2 = 0.f, f_cr = 0.f, f_ci = 0.f;
    if (ch == 0) {
        f_b0 = C.lp_b0; f_b1 = C.lp_b1; f_b2 = C.lp_b2; f_a1 = C.lp_a1; f_a2 = C.lp_a2;
    } else {
        f_b0 = 0.f;
#pragma unroll
        for (int c = 1; c < 8; ++c)
            if (ch == c) { f_b0 = C.bp_b0[c - 1]; f_cr = C.bp_cr[c - 1]; f_ci = C.bp_ci[c - 1]; }
    }
    const bool kp = (ch <= 2);

    // ---- init state: 128-grain tree (unchanged) + r sub-steps via M32 and S_r ----
    float s0 = 0.f, s1 = 0.f;
    if (act) {
        const int j128 = w * 16 + (L >> 2);
        const int r    = L & 3;
        const int g = j128 / GRP, i = j128 - g * GRP;
        double m00, m01, m10, m11;
        sel_M(ch, D, m00, m01, m10, m11);
        float2 ug = U[(size_t)g * SLOTS + slot];
        double u0 = ug.x, u1 = ug.y;
        const float2* Fb = ws_fin + (size_t)(g * GRP) * SLOTS + slot;
        float2 f[GRP - 1];
#pragma unroll
        for (int k = 0; k < GRP - 1; ++k)
            f[k] = (k < i) ? Fb[(size_t)k * SLOTS] : make_float2(0.f, 0.f);
#pragma unroll
        for (int k = 0; k < GRP - 1; ++k)
            if (k < i) {
                double t0 = (double)f[k].x + m00 * u0 + m01 * u1;
                double t1 = (double)f[k].y + m10 * u0 + m11 * u1;
                u0 = t0; u1 = t1;
            }
        // advance r (0..3) sub-steps of 32 samples: u = M32^r * u + S_r
        double e00, e01, e10, e11;
        sel_M(ch, E1, e00, e01, e10, e11);            // M32
#pragma unroll
        for (int k = 0; k < 3; ++k)
            if (k < r) {
                double t0 = e00 * u0 + e01 * u1;
                double t1 = e10 * u0 + e11 * u1;
                u0 = t0; u1 = t1;
            }
        if (r) {
            float2 sr = wsS[(size_t)(j128 * 3 + (r - 1)) * SLOTS + slot];
            u0 += (double)sr.x; u1 += (double)sr.y;
        }
        s0 = (float)u0; s1 = (float)u1;
    }

    // ---- compute 32 samples (4 at a time), write to swizzled per-wave tile ----
    const int swz = (L & 7) << 2;
    if (act) {
        if (ch == 0) {
#pragma unroll
            for (int q = 0; q < 8; ++q) {
                float4 xv = *reinterpret_cast<const float4*>(xsub + L * 32 + ((q * 4) ^ swz));
                float o[4];
                const float* xp = reinterpret_cast<const float*>(&xv);
#pragma unroll
                for (int k = 0; k < 4; ++k) {
                    float xvk = xp[k];
                    float y  = fmaf(f_b0, xvk, s0);
                    s0 = fmaf(f_b1, xvk, fmaf(-f_a1, y, s1));
                    s1 = fmaf(f_b2, xvk, -f_a2 * y);
                    o[k] = 2.0f * y;
                }
                *reinterpret_cast<float4*>(tile + L * 32 + ((q * 4) ^ swz)) =
                    make_float4(o[0], o[1], o[2], o[3]);
            }
        } else {
#pragma unroll
            for (int q = 0; q < 8; ++q) {
                float4 xv = *reinterpret_cast<const float4*>(xsub + L * 32 + ((q * 4) ^ swz));
                float o[4];
                const float* xp = reinterpret_cast<const float*>(&xv);
#pragma unroll
                for (int k = 0; k < 4; ++k) {
                    float xvk = xp[k];
                    float nyr = fmaf(f_cr, s0, fmaf(-f_ci, s1, f_b0 * xvk));
                    float nyi = fmaf(f_cr, s1, f_ci * s0);
                    s0 = nyr; s1 = nyi;
                    o[k] = kp ? 2.0f * nyr : 2.0f * sqrtf(fmaf(nyr, nyr, nyi * nyi));
                }
                *reinterpret_cast<float4*>(tile + L * 32 + ((q * 4) ^ swz)) =
                    make_float4(o[0], o[1], o[2], o[3]);
            }
        }
    }

    // wave-private tile; DS pipe in-order per wave -> compiler fence only (R8-verified)
    asm volatile("" ::: "memory");

    // ---- drain: 8 x 1KB contiguous wave-stores ----
    float* orow = out + (size_t)(n * 8 + ch) * T_LEN + w * WPW;
#pragma unroll
    for (int d = 0; d < 8; ++d) {
        int idx = d * 256 + L * 4;
        if (w * WPW + idx < T_LEN) {
            int row = idx >> 5;
            int col = (idx & 31) ^ ((row & 7) << 2);
            float4 v = *reinterpret_cast<const float4*>(tile + row * 32 + col);
            *reinterpret_cast<float4*>(orow + idx) = v;
        }
    }
}

extern "C" void kernel_launch(void* const* d_in, const int* in_sizes, int n_in,
                              void* d_out, int out_size, void* d_ws, size_t ws_size,
                              hipStream_t stream) {
    const float* x = (const float*)d_in[0];
    float* out = (float*)d_out;
    char* ws = (char*)d_ws;
    float2* ws_fin = (float2*)ws;                      //  3,072,000 B
    float2* wsS    = (float2*)(ws + 3072000);          //  9,216,000 B
    float2* Agg    = (float2*)(ws + 12288000);         //    204,800 B
    float2* Upre   = (float2*)(ws + 12492800);         //    204,800 B

    const double PI = 3.141592653589793;
    const double FS = 16000.0;
    CoefF C; CoefD D, D15, E1;
    {
        double K   = tan(PI * 2.5 / FS);
        double nrm = 1.0 / (1.0 + sqrt(2.0) * K + K * K);
        double a1  = 2.0 * (K * K - 1.0) * nrm;
        double a2  = (1.0 - sqrt(2.0) * K + K * K) * nrm;
        C.lp_b0 = (float)(K * K * nrm);
        C.lp_b1 = (float)(2.0 * K * K * nrm);
        C.lp_b2 = (float)(K * K * nrm);
        C.lp_a1 = (float)a1;
        C.lp_a2 = (float)a2;
        // A^32 (5 squarings) then A^128 (2 more)
        double p00 = -a1, p01 = 1.0, p10 = -a2, p11 = 0.0;
        for (int i = 0; i < 5; ++i) {
            double q00 = p00 * p00 + p01 * p10, q01 = p00 * p01 + p01 * p11;
            double q10 = p10 * p00 + p11 * p10, q11 = p10 * p01 + p11 * p11;
            p00 = q00; p01 = q01; p10 = q10; p11 = q11;
        }
        E1.p00 = p00; E1.p01 = p01; E1.p10 = p10; E1.p11 = p11;   // A^32
        for (int i = 0; i < 2; ++i) {
            double q00 = p00 * p00 + p01 * p10, q01 = p00 * p01 + p01 * p11;
            double q10 = p10 * p00 + p11 * p10, q11 = p10 * p01 + p11 * p11;
            p00 = q00; p01 = q01; p10 = q10; p11 = q11;
        }
        D.p00 = p00; D.p01 = p01; D.p10 = p10; D.p11 = p11;       // A^128
        // (A^128)^15
        double r00 = 1, r01 = 0, r10 = 0, r11 = 1, b00 = p00, b01 = p01, b10 = p10, b11 = p11;
        for (int e = 15; e > 0; e >>= 1) {
            if (e & 1) {
                double q00 = r00 * b00 + r01 * b10, q01 = r00 * b01 + r01 * b11;
                double q10 = r10 * b00 + r11 * b10, q11 = r10 * b01 + r11 * b11;
                r00 = q00; r01 = q01; r10 = q10; r11 = q11;
            }
            double q00 = b00 * b00 + b01 * b10, q01 = b00 * b01 + b01 * b11;
            double q10 = b10 * b00 + b11 * b10, q11 = b10 * b01 + b11 * b11;
            b00 = q00; b01 = q01; b10 = q10; b11 = q11;
        }
        D15.p00 = r00; D15.p01 = r01; D15.p10 = r10; D15.p11 = r11;

        double rr = (1.0 + 1.0 / 4.0) / (1.0 - 1.0 / 4.0);   // 5/3
        double mfc[7]; mfc[0] = 5.0; mfc[1] = 10.0;
        double f = 10.0 * rr;
        for (int m = 2; m < 7; ++m) { mfc[m] = f; f *= rr; }
        for (int m = 0; m < 7; ++m) {
            double bw = (mfc[m] <= 10.0) ? 5.0 : mfc[m] * 0.5;
            double e0 = exp(-PI * bw / FS);
            double th = 2.0 * PI * mfc[m] / FS;
            C.bp_b0[m] = (float)(1.0 - e0);
            C.bp_cr[m] = (float)(e0 * cos(th));
            C.bp_ci[m] = (float)(e0 * sin(th));
            double eL  = exp(-PI * bw * (double)L_CHUNK / FS);          // c^128
            double ang = th * (double)L_CHUNK;
            D.Pr[m] = eL * cos(ang);
            D.Pi[m] = eL * sin(ang);
            double eG  = exp(-PI * bw * (double)(L_CHUNK * GRP) / FS);  // c^1920
            double angG = th * (double)(L_CHUNK * GRP);
            D15.Pr[m] = eG * cos(angG);
            D15.Pi[m] = eG * sin(angG);
            double e32 = exp(-PI * bw * (double)SUB / FS);              // c^32
            double a32 = th * (double)SUB;
            E1.Pr[m] = e32 * cos(a32);
            E1.Pi[m] = e32 * sin(a32);
        }
    }

    const int smem1 = ROWS_PER_BLK * XS_STRIDE * 4;      // 33792 B
    const int smem3 = 9 * 64 * 32 * 4;                   // 73728 B -> 2 blocks/CU
    dim3 grid1(2, N_CHUNKS);
    mfb_p1<<<grid1, 512, smem1, stream>>>(x, C, ws_fin, wsS);
    mfb_groupsum<<<100, 256, 0, stream>>>(ws_fin, Agg, D);
    mfb_groupscan<<<4, 256, 0, stream>>>(Agg, Upre, D15);
    mfb_out<<<N_ROWS * N_WIN, 512, smem3, stream>>>(x, C, D, E1, D15,
                                                    ws_fin, wsS, Upre, out);
}

// Round 15
// 69.960 us; speedup vs baseline: 1.2440x; 1.2440x over previous
//
#include <hip/hip_runtime.h>
#include <cmath>

#define T_LEN 48000
#define L_CHUNK 128
#define N_CHUNKS 375
#define N_ROWS 124
#define SLOTS 1024          // 8 channels * 128 padded rows
#define ROWS_PER_BLK 64
#define XS_STRIDE 132       // 128 + 4 pad floats: 528 B rows, 16B-aligned
#define TR_STRIDE 20        // 16 + 4 pad floats: 80 B rows, 16B-aligned
#define GRP 15              // chunks per group
#define NGRP 25             // groups: GRP * NGRP == N_CHUNKS

struct CoefF {
    float lp_b0, lp_b1, lp_b2, lp_a1, lp_a2;
    float bp_b0[7], bp_cr[7], bp_ci[7];
};
struct CoefD {
    double p00, p01, p10, p11;   // LP propagator (2x2)
    double Pr[7], Pi[7];         // resonator propagators (complex)
};

// Select per-channel propagator as real 2x2 (wave-uniform ch, static indices).
__device__ __forceinline__ void sel_M(int ch, const CoefD& D,
                                      double& m00, double& m01, double& m10, double& m11) {
    if (ch == 0) {
        m00 = D.p00; m01 = D.p01; m10 = D.p10; m11 = D.p11;
    } else {
        double Pr = 0.0, Pi = 0.0;
#pragma unroll
        for (int c = 1; c < 8; ++c) if (ch == c) { Pr = D.Pr[c - 1]; Pi = D.Pi[c - 1]; }
        m00 = Pr; m01 = -Pi; m10 = Pi; m11 = Pr;
    }
}

// Phase 1 (FINAL=false): zero-init chunk scan, write final state only.
// Phase 3 (FINAL=true):  derive chunk-init from U[group] + <=14-step prefix over
//                        ws_fin (fused expand), scan, transpose-store outputs.
template <bool FINAL>
__global__ __launch_bounds__(512) void mfb_chunk(const float* __restrict__ x,
                                                 CoefF C, CoefD D,
                                                 float2* __restrict__ ws_fin,
                                                 const float2* __restrict__ U,
                                                 float* __restrict__ out) {
    extern __shared__ __align__(16) float smem[];
    float* xs = smem;                                  // [64][XS_STRIDE]
    const int t     = threadIdx.x;                     // 0..511
    const int j     = blockIdx.y;                      // chunk index
    const int n0    = (int)blockIdx.x * ROWS_PER_BLK;
    const int tbase = j * L_CHUNK;

    // ---- stage x tile into LDS, float4 both sides ----
#pragma unroll
    for (int i = 0; i < 4; ++i) {
        int g = i * 512 + t;            // float4-granule 0..2047
        int r = g >> 5, c = (g & 31) * 4;
        int n = n0 + r;
        float4 v = make_float4(0.f, 0.f, 0.f, 0.f);
        if (n < N_ROWS)
            v = *reinterpret_cast<const float4*>(x + (size_t)n * T_LEN + tbase + c);
        *reinterpret_cast<float4*>(xs + r * XS_STRIDE + c) = v;
    }
    __syncthreads();

    const int ch   = t >> 6;        // wave-uniform channel
    const int nn   = t & 63;        // lane = stream within tile
    const int n    = n0 + nn;
    const int slot = ch * 128 + n;
    float* trw = smem + ROWS_PER_BLK * XS_STRIDE + ch * (64 * TR_STRIDE);

    float f_b0, f_b1 = 0.f, f_b2 = 0.f, f_a1 = 0.f, f_a2 = 0.f, f_cr = 0.f, f_ci = 0.f;
    if (ch == 0) {
        f_b0 = C.lp_b0; f_b1 = C.lp_b1; f_b2 = C.lp_b2; f_a1 = C.lp_a1; f_a2 = C.lp_a2;
    } else {
        f_b0 = 0.f;
#pragma unroll
        for (int c = 1; c < 8; ++c)
            if (ch == c) { f_b0 = C.bp_b0[c - 1]; f_cr = C.bp_cr[c - 1]; f_ci = C.bp_ci[c - 1]; }
    }
    const bool kp = (ch <= 2);

    float s0 = 0.f, s1 = 0.f;
    if (FINAL) {
        // ---- fused expand: init state = U[g] advanced i = j%GRP chunk steps ----
        const int g = j / GRP, i = j - g * GRP;   // block-uniform
        double m00, m01, m10, m11;
        sel_M(ch, D, m00, m01, m10, m11);
        float2 ug = U[(size_t)g * SLOTS + slot];
        double u0 = ug.x, u1 = ug.y;
        const float2* Fb = ws_fin + (size_t)(g * GRP) * SLOTS + slot;
        float2 f[GRP - 1];
#pragma unroll
        for (int k = 0; k < GRP - 1; ++k)
            f[k] = (k < i) ? Fb[(size_t)k * SLOTS] : make_float2(0.f, 0.f);
#pragma unroll
        for (int k = 0; k < GRP - 1; ++k)
            if (k < i) {
                double t0 = (double)f[k].x + m00 * u0 + m01 * u1;
                double t1 = (double)f[k].y + m10 * u0 + m11 * u1;
                u0 = t0; u1 = t1;
            }
        s0 = (float)u0; s1 = (float)u1;
    }

    for (int b = 0; b < L_CHUNK / 16; ++b) {
        float4 xv4[4];
#pragma unroll
        for (int q = 0; q < 4; ++q)
            xv4[q] = *reinterpret_cast<const float4*>(xs + nn * XS_STRIDE + b * 16 + q * 4);
        const float* xv = reinterpret_cast<const float*>(xv4);

        float buf[16];
        if (ch == 0) {
#pragma unroll
            for (int k = 0; k < 16; ++k) {
                float xvk = xv[k];
                float y  = fmaf(f_b0, xvk, s0);
                s0 = fmaf(f_b1, xvk, fmaf(-f_a1, y, s1));
                s1 = fmaf(f_b2, xvk, -f_a2 * y);
                if (FINAL) buf[k] = 2.0f * y;
            }
        } else {
#pragma unroll
            for (int k = 0; k < 16; ++k) {
                float xvk = xv[k];
                float nyr = fmaf(f_cr, s0, fmaf(-f_ci, s1, f_b0 * xvk));
                float nyi = fmaf(f_cr, s1, f_ci * s0);
                s0 = nyr; s1 = nyi;
                if (FINAL)
                    buf[k] = kp ? 2.0f * nyr : 2.0f * sqrtf(fmaf(nyr, nyr, nyi * nyi));
            }
        }

        if (FINAL) {
            // Per-wave transpose tile (trw is wave-private). DS pipe is in-order
            // per wave -> compiler reorder fence suffices (R8-verified).
            asm volatile("" ::: "memory");
            *reinterpret_cast<float4*>(trw + nn * TR_STRIDE + 0)  = make_float4(buf[0], buf[1], buf[2], buf[3]);
            *reinterpret_cast<float4*>(trw + nn * TR_STRIDE + 4)  = make_float4(buf[4], buf[5], buf[6], buf[7]);
            *reinterpret_cast<float4*>(trw + nn * TR_STRIDE + 8)  = make_float4(buf[8], buf[9], buf[10], buf[11]);
            *reinterpret_cast<float4*>(trw + nn * TR_STRIDE + 12) = make_float4(buf[12], buf[13], buf[14], buf[15]);
            asm volatile("" ::: "memory");
#pragma unroll
            for (int s = 0; s < 4; ++s) {
                int rr = s * 16 + (nn >> 2);
                int kk = (nn & 3) * 4;
                int nrow = n0 + rr;
                if (nrow < N_ROWS) {
                    float4 v = *reinterpret_cast<const float4*>(trw + rr * TR_STRIDE + kk);
                    *reinterpret_cast<float4*>(out + (size_t)(nrow * 8 + ch) * T_LEN
                                               + tbase + b * 16 + kk) = v;
                }
            }
        }
    }
    if (!FINAL) ws_fin[(size_t)j * SLOTS + slot] = make_float2(s0, s1);
}

// ---- Tree combine, stage A: per (slot, group) aggregate A_g = sum M^(14-i) F_i ----
__global__ __launch_bounds__(256) void mfb_groupsum(const float2* __restrict__ ws_fin,
                                                    float2* __restrict__ A, CoefD D) {
    int tid = blockIdx.x * 256 + (int)threadIdx.x;   // 0..25599
    int s = tid & 1023, g = tid >> 10;
    double m00, m01, m10, m11;
    sel_M(s >> 7, D, m00, m01, m10, m11);

    const float2* base = ws_fin + (size_t)g * GRP * SLOTS + s;
    float2 f[GRP];
#pragma unroll
    for (int i = 0; i < GRP; ++i) f[i] = base[(size_t)i * SLOTS];

    double a0 = 0.0, a1 = 0.0;
#pragma unroll
    for (int i = 0; i < GRP; ++i) {
        double t0 = m00 * a0 + m01 * a1 + (double)f[i].x;
        double t1 = m10 * a0 + m11 * a1 + (double)f[i].y;
        a0 = t0; a1 = t1;
    }
    A[(size_t)g * SLOTS + s] = make_float2((float)a0, (float)a1);
}

// ---- stage B: per slot, exclusive prefix over 25 groups with M15 = M^(15*128) ----
__global__ __launch_bounds__(256) void mfb_groupscan(const float2* __restrict__ A,
                                                     float2* __restrict__ U, CoefD D15) {
    int s = blockIdx.x * 256 + (int)threadIdx.x;     // 0..1023
    double m00, m01, m10, m11;
    sel_M(s >> 7, D15, m00, m01, m10, m11);

    float2 f[NGRP];
#pragma unroll
    for (int g = 0; g < NGRP; ++g) f[g] = A[(size_t)g * SLOTS + s];

    double u0 = 0.0, u1 = 0.0;
#pragma unroll
    for (int g = 0; g < NGRP; ++g) {
        U[(size_t)g * SLOTS + s] = make_float2((float)u0, (float)u1);
        double t0 = (double)f[g].x + m00 * u0 + m01 * u1;
        double t1 = (double)f[g].y + m10 * u0 + m11 * u1;
        u0 = t0; u1 = t1;
    }
}

extern "C" void kernel_launch(void* const* d_in, const int* in_sizes, int n_in,
                              void* d_out, int out_size, void* d_ws, size_t ws_size,
                              hipStream_t stream) {
    const float* x = (const float*)d_in[0];
    float* out = (float*)d_out;
    char* ws = (char*)d_ws;
    float2* ws_fin  = (float2*)ws;                     // 3,072,000 B
    float2* Agg     = (float2*)(ws + 3072000);         //   204,800 B
    float2* Upre    = (float2*)(ws + 3276800);         //   204,800 B

    // ---- host-side coefficient computation (double, cast to f32 like the ref) ----
    const double PI = 3.141592653589793;
    const double FS = 16000.0;
    CoefF C; CoefD D, D15;
    {
        double K   = tan(PI * 2.5 / FS);
        double nrm = 1.0 / (1.0 + sqrt(2.0) * K + K * K);
        double a1  = 2.0 * (K * K - 1.0) * nrm;
        double a2  = (1.0 - sqrt(2.0) * K + K * K) * nrm;
        C.lp_b0 = (float)(K * K * nrm);
        C.lp_b1 = (float)(2.0 * K * K * nrm);
        C.lp_b2 = (float)(K * K * nrm);
        C.lp_a1 = (float)a1;
        C.lp_a2 = (float)a2;
        double p00 = -a1, p01 = 1.0, p10 = -a2, p11 = 0.0;
        for (int i = 0; i < 7; ++i) {   // A^128 by 7 squarings
            double q00 = p00 * p00 + p01 * p10, q01 = p00 * p01 + p01 * p11;
            double q10 = p10 * p00 + p11 * p10, q11 = p10 * p01 + p11 * p11;
            p00 = q00; p01 = q01; p10 = q10; p11 = q11;
        }
        D.p00 = p00; D.p01 = p01; D.p10 = p10; D.p11 = p11;
        // (A^128)^15 by square-and-multiply
        double r00 = 1, r01 = 0, r10 = 0, r11 = 1, b00 = p00, b01 = p01, b10 = p10, b11 = p11;
        for (int e = 15; e > 0; e >>= 1) {
            if (e & 1) {
                double q00 = r00 * b00 + r01 * b10, q01 = r00 * b01 + r01 * b11;
                double q10 = r10 * b00 + r11 * b10, q11 = r10 * b01 + r11 * b11;
                r00 = q00; r01 = q01; r10 = q10; r11 = q11;
            }
            double q00 = b00 * b00 + b01 * b10, q01 = b00 * b01 + b01 * b11;
            double q10 = b10 * b00 + b11 * b10, q11 = b10 * b01 + b11 * b11;
            b00 = q00; b01 = q01; b10 = q10; b11 = q11;
        }
        D15.p00 = r00; D15.p01 = r01; D15.p10 = r10; D15.p11 = r11;

        double rr = (1.0 + 1.0 / 4.0) / (1.0 - 1.0 / 4.0);   // 5/3
        double mfc[7]; mfc[0] = 5.0; mfc[1] = 10.0;
        double f = 10.0 * rr;
        for (int m = 2; m < 7; ++m) { mfc[m] = f; f *= rr; }
        for (int m = 0; m < 7; ++m) {
            double bw = (mfc[m] <= 10.0) ? 5.0 : mfc[m] * 0.5;
            double e0 = exp(-PI * bw / FS);
            double th = 2.0 * PI * mfc[m] / FS;
            C.bp_b0[m] = (float)(1.0 - e0);
            C.bp_cr[m] = (float)(e0 * cos(th));
            C.bp_ci[m] = (float)(e0 * sin(th));
            double eL  = exp(-PI * bw * (double)L_CHUNK / FS);       // chunk propagator
            double ang = th * (double)L_CHUNK;
            D.Pr[m] = eL * cos(ang);
            D.Pi[m] = eL * sin(ang);
            double eG  = exp(-PI * bw * (double)(L_CHUNK * GRP) / FS); // group propagator
            double angG = th * (double)(L_CHUNK * GRP);
            D15.Pr[m] = eG * cos(angG);
            D15.Pi[m] = eG * sin(angG);
        }
    }

    const int smem1 = ROWS_PER_BLK * XS_STRIDE * 4;                    // 33792 B
    const int smem3 = smem1 + 8 * 64 * TR_STRIDE * 4;                  // 74752 B
    dim3 grid(2, N_CHUNKS);
    mfb_chunk<false><<<grid, 512, smem1, stream>>>(x, C, D, ws_fin, nullptr, nullptr);
    mfb_groupsum<<<100, 256, 0, stream>>>(ws_fin, Agg, D);
    mfb_groupscan<<<4, 256, 0, stream>>>(Agg, Upre, D15);
    mfb_chunk<true><<<grid, 512, smem3, stream>>>(x, C, D, ws_fin, Upre, out);
}